// Round 4
// baseline (373.835 us; speedup 1.0000x reference)
//
#include <hip/hip_runtime.h>
#include <hip/hip_bf16.h>
#include <math.h>

typedef unsigned short u16;
typedef unsigned int u32;
typedef __attribute__((ext_vector_type(8))) short bf16x8;   // 8 bf16 = 4 VGPRs
typedef __attribute__((ext_vector_type(4))) float f32x4;

constexpr int Bc = 2, Sc = 2048, Dc = 2048, Hc = 16, HDc = 128;
constexpr int Mc = Bc * Sc;                     // 4096
constexpr float SCALE = 0.08838834764831845f;   // 1/sqrt(128)

__device__ inline u16 f2bf(float f) {
  __hip_bfloat16 h = __float2bfloat16(f);
  return __builtin_bit_cast(u16, h);
}

typedef const __attribute__((address_space(1))) u32 glb_u32;
typedef __attribute__((address_space(3))) u32 lds_u32;
__device__ inline void gload16(const void* g, void* l) {
  // async global->LDS, 16B/lane; LDS dest is wave-uniform base + lane*16
  __builtin_amdgcn_global_load_lds((glb_u32*)g, (lds_u32*)l, 16, 0, 0);
}

// ---------------- fp32 -> bf16 convert (hidden + 4 weights) ----------------
__global__ __launch_bounds__(256) void cvt5(
    const float* __restrict__ s0, u16* __restrict__ d0, int n0,
    const float* __restrict__ s1, u16* __restrict__ d1, int n1,
    const float* __restrict__ s2, u16* __restrict__ d2, int n2,
    const float* __restrict__ s3, u16* __restrict__ d3, int n3,
    const float* __restrict__ s4, u16* __restrict__ d4, int n4) {
  int i = blockIdx.x * 256 + threadIdx.x;   // float4 index
  const float* s; u16* d;
  if (i < n0) { s = s0; d = d0; }
  else { i -= n0;
    if (i < n1) { s = s1; d = d1; }
    else { i -= n1;
      if (i < n2) { s = s2; d = d2; }
      else { i -= n2;
        if (i < n3) { s = s3; d = d3; }
        else { i -= n3;
          if (i >= n4) return;
          s = s4; d = d4; } } } }
  float4 v = reinterpret_cast<const float4*>(s)[i];
  ushort4 o;
  o.x = f2bf(v.x); o.y = f2bf(v.y); o.z = f2bf(v.z); o.w = f2bf(v.w);
  reinterpret_cast<ushort4*>(d)[i] = o;
}

// ---------------- bf16 MFMA GEMM: C[M,N] = A[M,K] * W[N,K]^T + bias --------
// MODE 0: bf16 scatter to [B,H,S,HD], scaled; MODE 1: fp32 [M,N] to d_out;
// MODE 2: bf16 transposed scatter to [B,H,HD,S] (V^T). 1D grid 512, XCD-swz.
constexpr int GBM = 128, GBN = 128, GBK = 64;

template <int MODE>
__global__ __launch_bounds__(256) void gemm_bf16(
    const u16* __restrict__ A, const u16* __restrict__ W,
    const float* __restrict__ bias, void* __restrict__ outp, float scale) {
  __shared__ u16 smem[17408];     // As[8192] | Bs[8192]; epilogue CT[128*136]
  u16* As = smem;
  u16* Bs = smem + 8192;
  char* Asb = (char*)As;
  char* Bsb = (char*)Bs;
  const int t = threadIdx.x;
  const int w = t >> 6, lane = t & 63, g = lane >> 4, c = lane & 15;
  const int wm = w >> 1, wn = w & 1;
  const int bid = blockIdx.x;
  const int swz = (bid & 7) * 64 + (bid >> 3);   // XCD-chunked, 512%8==0
  const int m0 = (swz >> 4) * GBM, n0 = (swz & 15) * GBN;

  f32x4 acc[4][4];
#pragma unroll
  for (int m = 0; m < 4; ++m)
#pragma unroll
    for (int n = 0; n < 4; ++n) acc[m][n] = 0.f;

  for (int k0 = 0; k0 < Dc; k0 += GBK) {
#pragma unroll
    for (int i = 0; i < 4; ++i) {
      int u = i * 256 + t;
      int row = u >> 3, cu = u & 7;
      int ub = i * 256 + (t & 192);           // wave-uniform unit base
      gload16(A + (size_t)(m0 + row) * Dc + k0 + cu * 8, Asb + ub * 16);
      gload16(W + (size_t)(n0 + row) * Dc + k0 + cu * 8, Bsb + ub * 16);
    }
    __syncthreads();
#pragma unroll
    for (int s = 0; s < 2; ++s) {
      bf16x8 af[4], bfv[4];
#pragma unroll
      for (int m = 0; m < 4; ++m)
        af[m] = *(const bf16x8*)(Asb + (wm * 64 + m * 16 + c) * 128 + s * 64 + g * 16);
#pragma unroll
      for (int n = 0; n < 4; ++n)
        bfv[n] = *(const bf16x8*)(Bsb + (wn * 64 + n * 16 + c) * 128 + s * 64 + g * 16);
#pragma unroll
      for (int m = 0; m < 4; ++m)
#pragma unroll
        for (int n = 0; n < 4; ++n)
          acc[m][n] = __builtin_amdgcn_mfma_f32_16x16x32_bf16(af[m], bfv[n], acc[m][n], 0, 0, 0);
    }
    __syncthreads();
  }

  if (MODE == 2) {
    // transpose through LDS, then coalesced bf16 writes to [B,H,HD,S]
    u16* CT = smem;                           // [128 d][136 pitch] u16
    __syncthreads();
#pragma unroll
    for (int m = 0; m < 4; ++m)
#pragma unroll
      for (int n = 0; n < 4; ++n) {
        int lcol = wn * 64 + n * 16 + c;      // d (local)
        float bv = bias[n0 + lcol];
#pragma unroll
        for (int r = 0; r < 4; ++r) {
          int lrow = wm * 64 + m * 16 + g * 4 + r;   // s (local)
          CT[lcol * 136 + lrow] = f2bf(acc[m][n][r] + bv);
        }
      }
    __syncthreads();
    const int b = m0 >> 11, h = n0 >> 7, s0 = m0 & (Sc - 1);
    u16* op = (u16*)outp;
#pragma unroll
    for (int i = 0; i < 8; ++i) {
      int u = i * 256 + t;
      int d = u >> 4, su = u & 15;
      float4 v4 = *(const float4*)(&CT[d * 136 + su * 8]);
      *(float4*)(&op[((size_t)((b * Hc + h) * HDc) + d) * Sc + s0 + su * 8]) = v4;
    }
    return;
  }

#pragma unroll
  for (int m = 0; m < 4; ++m)
#pragma unroll
    for (int n = 0; n < 4; ++n) {
      int col = n0 + wn * 64 + n * 16 + c;
      float bv = bias[col];
#pragma unroll
      for (int r = 0; r < 4; ++r) {
        int row = m0 + wm * 64 + m * 16 + g * 4 + r;
        float v = (acc[m][n][r] + bv) * scale;
        if (MODE == 0) {
          int b = row >> 11, si = row & (Sc - 1);
          int h = col >> 7, d = col & (HDc - 1);
          ((u16*)outp)[((size_t)((b * Hc + h) * Sc + si)) * HDc + d] = f2bf(v);
        } else {
          ((float*)outp)[(size_t)row * Dc + col] = v;
        }
      }
    }
}

// ---------------- bf16 MFMA flash attention (v3) ----------------
// 1D grid 1024 (XCD-swz: 4 heads per XCD), 256 thr = 4 waves, 16 q-rows/wave.
// Swapped QK^T (S^T = K*Q^T) -> P stays in registers; shfl redistribution to
// PV B-operand. Double-buffered K/V staging, ONE barrier per tile.
__global__ __launch_bounds__(256) void attn_mfma(
    const u16* __restrict__ Q, const u16* __restrict__ K,
    const u16* __restrict__ VT, const float* __restrict__ mask,
    u16* __restrict__ outb) {
  __shared__ u16 Ks0[64 * 128], Ks1[64 * 128];   // 16KB each
  __shared__ u16 Vt0[64 * 128], Vt1[64 * 128];   // (Vt: [d=128][k=64])
  const int t = threadIdx.x, w = t >> 6, lane = t & 63, g = lane >> 4, c = lane & 15;
  const int bid = blockIdx.x;
  const int nid = (bid & 7) * 128 + (bid >> 3);  // 1024%8==0 bijective
  const int bh = nid >> 5;                       // head 0..31 (4 heads/XCD)
  const int q0 = (nid & 31) * 64;
  const int bq = bh >> 4, h = bh & 15;
  const u16* Qp = Q + ((size_t)bh << 18);
  const u16* Kp = K + ((size_t)bh << 18);
  const u16* VTp = VT + ((size_t)bh << 18);

  // Q fragments (pre-scaled by 1/sqrt(HD) in Q-GEMM); B-operand of swapped QK^T
  bf16x8 qf[4];
  {
    int qr = q0 + w * 16 + c;
#pragma unroll
    for (int d0 = 0; d0 < 4; ++d0)
      qf[d0] = *(const bf16x8*)(Qp + (size_t)qr * HDc + d0 * 32 + g * 8);
  }

  f32x4 po[8];                     // O^T acc: d = m*16+g*4+r, q = c
#pragma unroll
  for (int m = 0; m < 8; ++m) po[m] = 0.f;
  float lsum = 0.f;                // per-lane partial row-sum for q = c
  const float* mrow = mask + ((size_t)bq * Sc + q0 + w * 16 + c) * Sc;

  auto STAGE = [&](u16* KsD, u16* VtD, int kt2) {
    const int k0 = kt2 * 64;
#pragma unroll
    for (int i = 0; i < 4; ++i) {
      int u = i * 256 + t, row = u >> 4, p = u & 15;
      int cu = (p & 8) | ((p ^ row) & 7);
      gload16(Kp + (size_t)(k0 + row) * HDc + cu * 8,
              (char*)KsD + (i * 256 + (t & 192)) * 16);
    }
#pragma unroll
    for (int i = 0; i < 4; ++i) {
      int u = i * 256 + t, d = u >> 3, p = u & 7;
      int cu = (p ^ d) & 7;
      gload16(VTp + (size_t)d * Sc + k0 + cu * 8,
              (char*)VtD + (i * 256 + (t & 192)) * 16);
    }
  };
  auto MLOAD = [&](float4* mk, int kt2) {
#pragma unroll
    for (int n = 0; n < 4; ++n)
      mk[n] = *(const float4*)(mrow + kt2 * 64 + n * 16 + g * 4);
  };
  const int srcA = ((lane & 16) << 1) | c;       // (g&1)*32 + c
  const int srcB = srcA + 16;
  const bool hiN = lane >= 32;                   // g>>1

  auto TILE = [&](const u16* KsS, const u16* VtS, const float4* mk) {
    const char* Ksb = (const char*)KsS;
    const char* Vtb = (const char*)VtS;
    f32x4 sfr[4];
#pragma unroll
    for (int n = 0; n < 4; ++n) sfr[n] = 0.f;
    __builtin_amdgcn_s_setprio(1);
#pragma unroll
    for (int ds = 0; ds < 4; ++ds)
#pragma unroll
      for (int n = 0; n < 4; ++n) {
        int row = n * 16 + c;
        int cu = ds * 4 + g;
        int scu = (cu & 8) | ((cu ^ row) & 7);
        bf16x8 kf = *(const bf16x8*)(Ksb + row * 256 + scu * 16);
        // swapped: S^T[k][q]; C row = k-local n*16+g*4+r, col = q = c
        sfr[n] = __builtin_amdgcn_mfma_f32_16x16x32_bf16(kf, qf[ds], sfr[n], 0, 0, 0);
      }
    __builtin_amdgcn_s_setprio(0);

    // P = exp(S + mask) in-register; pack bf16 pairs (k contiguous in r)
    u32 w01[4], w23[4];
    float lp = 0.f;
#pragma unroll
    for (int n = 0; n < 4; ++n) {
      float p0 = __expf(sfr[n][0] + mk[n].x);
      float p1 = __expf(sfr[n][1] + mk[n].y);
      float p2 = __expf(sfr[n][2] + mk[n].z);
      float p3 = __expf(sfr[n][3] + mk[n].w);
      lp += (p0 + p1) + (p2 + p3);
      w01[n] = (u32)f2bf(p0) | ((u32)f2bf(p1) << 16);
      w23[n] = (u32)f2bf(p2) | ((u32)f2bf(p3) << 16);
    }
    lsum += lp;

    // redistribute to PV B-operand: lane (g,c) needs k = s2*32+g*8+j, q=c
#pragma unroll
    for (int s2 = 0; s2 < 2; ++s2) {
      u32 a0 = __shfl(w01[s2 * 2], srcA, 64), a0b = __shfl(w01[s2 * 2 + 1], srcA, 64);
      u32 a1 = __shfl(w23[s2 * 2], srcA, 64), a1b = __shfl(w23[s2 * 2 + 1], srcA, 64);
      u32 b0 = __shfl(w01[s2 * 2], srcB, 64), b0b = __shfl(w01[s2 * 2 + 1], srcB, 64);
      u32 b1 = __shfl(w23[s2 * 2], srcB, 64), b1b = __shfl(w23[s2 * 2 + 1], srcB, 64);
      uint4 pw;
      pw.x = hiN ? a0b : a0;
      pw.y = hiN ? a1b : a1;
      pw.z = hiN ? b0b : b0;
      pw.w = hiN ? b1b : b1;
      bf16x8 pf = __builtin_bit_cast(bf16x8, pw);
      __builtin_amdgcn_s_setprio(1);
#pragma unroll
      for (int m = 0; m < 8; ++m) {
        int d = m * 16 + c;
        int scuv = ((s2 * 4 + g) ^ (d & 7)) & 7;
        bf16x8 vf = *(const bf16x8*)(Vtb + d * 128 + scuv * 16);
        po[m] = __builtin_amdgcn_mfma_f32_16x16x32_bf16(vf, pf, po[m], 0, 0, 0);
      }
      __builtin_amdgcn_s_setprio(0);
    }
  };

  float4 mA[4], mB[4];
  STAGE(Ks0, Vt0, 0);
  MLOAD(mA, 0);
  __syncthreads();                 // drains prologue stage (vmcnt 0)

#pragma unroll 1
  for (int kt = 0; kt < 32; kt += 2) {
    STAGE(Ks1, Vt1, kt + 1);       // prefetch tile kt+1 under tile kt compute
    MLOAD(mB, kt + 1);
    TILE(Ks0, Vt0, mA);
    __syncthreads();               // drains buf1 stage; releases buf0
    if (kt + 2 < 32) { STAGE(Ks0, Vt0, kt + 2); MLOAD(mA, kt + 2); }
    TILE(Ks1, Vt1, mB);
    __syncthreads();
  }

  // final l: reduce across the 4 g-groups holding q=c partials
  lsum += __shfl_xor(lsum, 16, 64);
  lsum += __shfl_xor(lsum, 32, 64);
  const float rlq = 1.0f / lsum;
  const int qg = q0 + w * 16 + c;
  u16* obase = outb + ((size_t)(bq * Sc + qg)) * Dc + h * HDc;
#pragma unroll
  for (int m = 0; m < 8; ++m) {
    ushort4 o4;
    o4.x = f2bf(po[m][0] * rlq);
    o4.y = f2bf(po[m][1] * rlq);
    o4.z = f2bf(po[m][2] * rlq);
    o4.w = f2bf(po[m][3] * rlq);
    *(ushort4*)(obase + m * 16 + g * 4) = o4;
  }
}

// ---------------- launch ----------------
extern "C" void kernel_launch(void* const* d_in, const int* in_sizes, int n_in,
                              void* d_out, int out_size, void* d_ws,
                              size_t ws_size, hipStream_t stream) {
  const float* hs   = (const float*)d_in[0];
  const float* mask = (const float*)d_in[1];
  const float* Wq   = (const float*)d_in[2];
  const float* bqp  = (const float*)d_in[3];
  const float* Wk   = (const float*)d_in[4];
  const float* bkp  = (const float*)d_in[5];
  const float* Wv   = (const float*)d_in[6];
  const float* bvp  = (const float*)d_in[7];
  const float* Wo   = (const float*)d_in[8];
  const float* bop  = (const float*)d_in[9];

  u16* Xb  = (u16*)d_ws;                 // [4096][2048] bf16
  u16* Wqb = Xb + (size_t)Mc * Dc;
  u16* Wkb = Wqb + (size_t)Dc * Dc;
  u16* Wvb = Wkb + (size_t)Dc * Dc;
  u16* Wob = Wvb + (size_t)Dc * Dc;
  u16* qb  = Wob + (size_t)Dc * Dc;      // [B,H,S,HD] bf16 (pre-scaled)
  u16* kb  = qb + (size_t)Mc * Dc;       // [B,H,S,HD] bf16
  u16* vtb = kb + (size_t)Mc * Dc;       // [B,H,HD,S] bf16
  u16* ab  = vtb + (size_t)Mc * Dc;      // [B,S,D] bf16

  const int nh4 = Mc * Dc / 4;
  const int nw4 = Dc * Dc / 4;
  cvt5<<<dim3((nh4 + 4 * nw4) / 256), dim3(256), 0, stream>>>(
      hs, Xb, nh4, Wq, Wqb, nw4, Wk, Wkb, nw4, Wv, Wvb, nw4, Wo, Wob, nw4);

  dim3 blk(256);
  dim3 gg(512);                          // 1D, XCD-swizzled in-kernel
  gemm_bf16<0><<<gg, blk, 0, stream>>>(Xb, Wqb, bqp, qb, SCALE);
  gemm_bf16<0><<<gg, blk, 0, stream>>>(Xb, Wkb, bkp, kb, 1.0f);
  gemm_bf16<2><<<gg, blk, 0, stream>>>(Xb, Wvb, bvp, vtb, 1.0f);
  attn_mfma<<<dim3(1024), blk, 0, stream>>>(qb, kb, vtb, mask, ab);
  gemm_bf16<1><<<gg, blk, 0, stream>>>(ab, Wob, bop, d_out, 1.0f);
}